// Round 4
// baseline (157.019 us; speedup 1.0000x reference)
//
#include <hip/hip_runtime.h>

#define D 128
#define N_TILES 2080        // 64*65/2 upper-triangular 128x128 blocks

typedef __attribute__((ext_vector_type(8))) short short8;   // 8 x bf16 (4 VGPRs)
typedef __attribute__((ext_vector_type(4))) float float4v;  // 4 x f32 acc

static __device__ __forceinline__ unsigned short f2bf(float f) {
    unsigned int u = __float_as_uint(f);
    unsigned int r = (u + 0x7fffu + ((u >> 16) & 1u)) >> 16;  // RNE
    return (unsigned short)r;
}

// ws float-index layout:
//   [0..1]  sumsq (double)     [2] cnt1 (uint)   [3] cnt2 (uint)   [4] c4
//   [8..135]   colsum[128]
//   [256..8447]  rowsq[8192]
//   [8448..10527] partial[2080]
//   [16384..]   xbf bf16 copy of X (2 MB)
// First 4 KB zeroed by a memset node each call.

// ---- K1: fused rowsq + bf16 convert + column sums; last block computes c4 ----
__global__ __launch_bounds__(256) void k_stats(const float* __restrict__ src,
                                               const float* __restrict__ tgt,
                                               float* __restrict__ wsf,
                                               unsigned int* __restrict__ xbf) {
    double* sumsq = (double*)wsf;
    unsigned int* cnt = (unsigned int*)(wsf + 2);
    float* colsum = wsf + 8;
    float* rowsq = wsf + 256;

    const int tid = threadIdx.x, lane = tid & 63, wv = tid >> 6;
    float cx = 0.f, cy = 0.f, sq = 0.f;
    #pragma unroll
    for (int i = 0; i < 4; ++i) {
        int r = blockIdx.x * 16 + wv * 4 + i;
        const float* Xr = (r < 4096) ? src + (size_t)r * D : tgt + (size_t)(r - 4096) * D;
        float2 f = ((const float2*)Xr)[lane];
        xbf[r * 64 + lane] = (unsigned)f2bf(f.x) | ((unsigned)f2bf(f.y) << 16);
        float s = f.x * f.x + f.y * f.y;
        sq += s; cx += f.x; cy += f.y;
        #pragma unroll
        for (int off = 32; off; off >>= 1) s += __shfl_down(s, off);
        if (lane == 0) rowsq[r] = s;
    }
    __shared__ float csx[4][64], csy[4][64], ssh[4];
    __shared__ int lastS;
    float t = sq;
    #pragma unroll
    for (int off = 32; off; off >>= 1) t += __shfl_down(t, off);
    csx[wv][lane] = cx; csy[wv][lane] = cy;
    if (lane == 0) ssh[wv] = t;
    __syncthreads();
    if (wv == 0) {
        float a = csx[0][lane] + csx[1][lane] + csx[2][lane] + csx[3][lane];
        float b = csy[0][lane] + csy[1][lane] + csy[2][lane] + csy[3][lane];
        atomicAdd(&colsum[2 * lane], a);
        atomicAdd(&colsum[2 * lane + 1], b);
        if (lane == 0) atomicAdd(sumsq, (double)(ssh[0] + ssh[1] + ssh[2] + ssh[3]));
        __threadfence();                                   // release our atomics
        if (lane == 0) lastS = (atomicAdd(cnt, 1u) == 511u) ? 1 : 0;
    }
    __syncthreads();
    if (lastS && wv == 0) {
        __threadfence();                                   // acquire others' atomics
        float c0 = colsum[lane], c1 = colsum[64 + lane];
        float v = c0 * c0 + c1 * c1;
        #pragma unroll
        for (int off = 32; off; off >>= 1) v += __shfl_down(v, off);
        if (lane == 0) {
            double ss = *sumsq;
            double sumL2 = 2.0 * 8192.0 * ss - 2.0 * (double)v;
            double bw = sumL2 / (8192.0 * 8192.0 - 8192.0) / 4.0;  // /KERNEL_MUL^(5/2)
            wsf[4] = (float)(-1.4426950408889634 / (bw * 16.0));   // c4
        }
    }
}

// ---- K2: tiled gram + fused 5-scale RBF epilogue + last-block final reduce ----
// LDS: 16B chunk c of row r lives at chunk slot (c ^ (r&7)) -> conflict-free b128 reads,
// contiguous global_load_lds deposit (swizzle carried by per-lane global address).
__global__ __launch_bounds__(256, 2) void mmd_main(const unsigned short* __restrict__ xbf,
                                                   float* __restrict__ wsf,
                                                   float* __restrict__ out) {
    __shared__ unsigned short ldsA[128 * D];  // 32 KB
    __shared__ unsigned short ldsB[128 * D];  // 32 KB (total 64 KB -> 2 blocks/CU)

    const float* rowsq = wsf + 256;
    float* partial = wsf + 8448;
    unsigned int* cnt2 = (unsigned int*)(wsf + 3);

    // triangular block index -> (bi <= bj)
    int t = blockIdx.x;
    int bi = (int)((129.0 - sqrt(129.0 * 129.0 - 8.0 * (double)t)) * 0.5);
    auto base = [](int b) { return (b * (129 - b)) >> 1; };
    while (base(bi + 1) <= t) ++bi;
    while (base(bi) > t) --bi;
    int bj = bi + (t - base(bi));

    const int tid = threadIdx.x, lane = tid & 63, wv = tid >> 6;
    const int quad = lane >> 4, mrow = lane & 15;

    const unsigned short* XA = xbf + (size_t)bi * 128 * D;
    const unsigned short* XB = xbf + (size_t)bj * 128 * D;
    #pragma unroll
    for (int j = 0; j < 8; ++j) {
        int slot = wv * 512 + j * 64 + lane;           // destination 16B slot
        int rr = slot >> 4, sc = slot & 15;
        int cc = sc ^ (rr & 7);                        // which global chunk lands here
        const unsigned short* gA = XA + rr * D + cc * 8;
        const unsigned short* gB = XB + rr * D + cc * 8;
        int lbase = (wv * 512 + j * 64) * 8;           // wave-uniform LDS base (ushort idx)
        __builtin_amdgcn_global_load_lds((const __attribute__((address_space(1))) void*)gA,
                                         (__attribute__((address_space(3))) void*)&ldsA[lbase],
                                         16, 0, 0);
        __builtin_amdgcn_global_load_lds((const __attribute__((address_space(1))) void*)gB,
                                         (__attribute__((address_space(3))) void*)&ldsB[lbase],
                                         16, 0, 0);
    }
    float c4 = wsf[4];
    __syncthreads();

    const int wm = wv & 1, wn = wv >> 1;  // 2x2 wave grid, 64x64 per wave

    float4v accf[4][4];
    #pragma unroll
    for (int mt = 0; mt < 4; ++mt)
        #pragma unroll
        for (int nt = 0; nt < 4; ++nt)
            accf[mt][nt] = (float4v){0.f, 0.f, 0.f, 0.f};

    const int xkey = (mrow & 7);
    #pragma unroll
    for (int kc = 0; kc < 4; ++kc) {
        const int c = kc * 4 + quad;
        const int co = (c ^ xkey) * 8;
        short8 af[4], bfr[4];
        #pragma unroll
        for (int mt = 0; mt < 4; ++mt)
            af[mt] = *(const short8*)&ldsA[(wm * 64 + mt * 16 + mrow) * D + co];
        #pragma unroll
        for (int nt = 0; nt < 4; ++nt)
            bfr[nt] = *(const short8*)&ldsB[(wn * 64 + nt * 16 + mrow) * D + co];
        #pragma unroll
        for (int mt = 0; mt < 4; ++mt)
            #pragma unroll
            for (int nt = 0; nt < 4; ++nt)
                accf[mt][nt] = __builtin_amdgcn_mfma_f32_16x16x32_bf16(af[mt], bfr[nt], accf[mt][nt], 0, 0, 0);
    }

    // epilogue: L2 -> sum of 5 exps (one v_exp + 4 squarings)
    const float* rsqA = rowsq + bi * 128;
    const float* rsqB = rowsq + bj * 128;
    float part = 0.f;
    #pragma unroll
    for (int mt = 0; mt < 4; ++mt) {
        float rA[4];
        #pragma unroll
        for (int r = 0; r < 4; ++r) rA[r] = rsqA[wm * 64 + mt * 16 + quad * 4 + r];
        #pragma unroll
        for (int nt = 0; nt < 4; ++nt) {
            float rB = rsqB[wn * 64 + nt * 16 + mrow];
            float4v d = accf[mt][nt];
            #pragma unroll
            for (int r = 0; r < 4; ++r) {
                float L2 = rA[r] + rB - 2.f * d[r];
                float e1 = __builtin_amdgcn_exp2f(L2 * c4);
                float e2 = e1 * e1, e4 = e2 * e2, e8 = e4 * e4, e16 = e8 * e8;
                part += ((e1 + e2) + (e4 + e8)) + e16;
            }
        }
    }
    #pragma unroll
    for (int off = 32; off; off >>= 1) part += __shfl_down(part, off);

    __syncthreads();               // tile data dead; reuse ldsA as scratch
    float* red = (float*)ldsA;     // red[0..3] wave partials; ((int*)red)[8] last-flag
    double* dred = (double*)(red + 16);
    if (lane == 0) red[wv] = part;
    __syncthreads();
    if (tid == 0) {
        float s = (red[0] + red[1]) + (red[2] + red[3]);
        float wgt = ((bi < 32) == (bj < 32)) ? 1.f : -1.f;  // XX/YY vs XY/YX sign
        if (bi != bj) wgt *= 2.f;                           // symmetric off-diagonal
        partial[t] = wgt * s;
        __threadfence();                                    // release partial
        ((int*)red)[8] = (atomicAdd(cnt2, 1u) == (unsigned)(N_TILES - 1)) ? 1 : 0;
    }
    __syncthreads();
    if (((int*)red)[8]) {
        __threadfence();                                    // acquire all partials
        double s = 0.0;
        for (int i = tid; i < N_TILES; i += 256) s += (double)partial[i];
        #pragma unroll
        for (int off = 32; off; off >>= 1) s += __shfl_down(s, off);
        if (lane == 0) dred[wv] = s;
        __syncthreads();
        if (tid == 0)
            out[0] = (float)(((dred[0] + dred[1]) + (dred[2] + dred[3])) *
                             (1.0 / (4096.0 * 4096.0)));
    }
}

extern "C" void kernel_launch(void* const* d_in, const int* in_sizes, int n_in,
                              void* d_out, int out_size, void* d_ws, size_t ws_size,
                              hipStream_t stream) {
    const float* src = (const float*)d_in[0];
    const float* tgt = (const float*)d_in[1];
    float* wsf = (float*)d_ws;
    unsigned int* xbf = (unsigned int*)(wsf + 16384);  // bf16 X copy at byte 64K (2 MB)

    hipMemsetAsync(d_ws, 0, 4096, stream);             // zero accumulators + counters
    hipLaunchKernelGGL(k_stats, dim3(512), dim3(256), 0, stream, src, tgt, wsf, xbf);
    hipLaunchKernelGGL(mmd_main, dim3(N_TILES), dim3(256), 0, stream,
                       (const unsigned short*)xbf, wsf, (float*)d_out);
}

// Round 5
// 123.784 us; speedup vs baseline: 1.2685x; 1.2685x over previous
//
#include <hip/hip_runtime.h>

#define D 128
#define N_TILES 2080        // 64*65/2 upper-triangular 128x128 blocks

typedef __attribute__((ext_vector_type(8))) short short8;   // 8 x bf16 (4 VGPRs)
typedef __attribute__((ext_vector_type(4))) float float4v;  // 4 x f32 acc

static __device__ __forceinline__ unsigned short f2bf(float f) {
    unsigned int u = __float_as_uint(f);
    unsigned int r = (u + 0x7fffu + ((u >> 16) & 1u)) >> 16;  // RNE
    return (unsigned short)r;
}

// ws float-index layout (no counters, no atomics -> nothing needs zeroing):
//   [4]              c4                     (written by k2)
//   [8..263]         ssq[256]               (k1 block partial sum-of-squares)
//   [512..33279]     colpart[256*128]       (k1 block partial column sums)
//   [33280..41471]   rowsq[8192]            (k1)
//   [41472..43551]   partial[2080]          (mmd)
//   [65536..]        xbf: bf16 X, PRE-SWIZZLED rows (2 MB)

// ---- K1: rowsq + bf16 convert (pre-swizzled) + block-partial column sums ----
// 256 blocks x 256 threads; block handles 32 rows (wave wv: rows b*32+wv*8+i).
__global__ __launch_bounds__(256) void k_stats(const float* __restrict__ src,
                                               const float* __restrict__ tgt,
                                               float* __restrict__ wsf,
                                               unsigned int* __restrict__ xbf) {
    float* ssq = wsf + 8;
    float* colpart = wsf + 512;
    float* rowsq = wsf + 33280;

    const int tid = threadIdx.x, lane = tid & 63, wv = tid >> 6;
    float cx = 0.f, cy = 0.f, sq = 0.f;
    #pragma unroll
    for (int i = 0; i < 8; ++i) {
        int r = blockIdx.x * 32 + wv * 8 + i;
        const float* Xr = (r < 4096) ? src + (size_t)r * D : tgt + (size_t)(r - 4096) * D;
        float2 f = ((const float2*)Xr)[lane];
        // pre-swizzle: 16B chunk c of row r stored at chunk slot c^(r&7)
        int w = (((lane >> 2) ^ (r & 7)) << 2) | (lane & 3);
        xbf[r * 64 + w] = (unsigned)f2bf(f.x) | ((unsigned)f2bf(f.y) << 16);
        float s = f.x * f.x + f.y * f.y;
        sq += s; cx += f.x; cy += f.y;
        #pragma unroll
        for (int off = 32; off; off >>= 1) s += __shfl_down(s, off);
        if (lane == 0) rowsq[r] = s;
    }
    __shared__ float csx[4][64], csy[4][64], ssh[4];
    float t = sq;
    #pragma unroll
    for (int off = 32; off; off >>= 1) t += __shfl_down(t, off);
    csx[wv][lane] = cx; csy[wv][lane] = cy;
    if (lane == 0) ssh[wv] = t;
    __syncthreads();
    if (wv == 0) {
        float a = csx[0][lane] + csx[1][lane] + csx[2][lane] + csx[3][lane];
        float b = csy[0][lane] + csy[1][lane] + csy[2][lane] + csy[3][lane];
        ((float2*)(colpart + blockIdx.x * 128))[lane] = make_float2(a, b);
        if (lane == 0) ssq[blockIdx.x] = ssh[0] + ssh[1] + ssh[2] + ssh[3];
    }
}

// ---- K2: reduce k1 partials -> bandwidth constant c4 ----
__global__ __launch_bounds__(256) void k_c4(float* __restrict__ wsf) {
    const float* ssq = wsf + 8;
    const float* colpart = wsf + 512;
    const int tid = threadIdx.x, lane = tid & 63;

    double s = (double)ssq[tid];                 // 256 block partials
    #pragma unroll
    for (int off = 32; off; off >>= 1) s += __shfl_down(s, off);
    __shared__ double dsh[4];
    __shared__ float csum[128];
    if (lane == 0) dsh[tid >> 6] = s;

    int c = tid & 127, h = tid >> 7;             // column c, half h of blocks
    float cs = 0.f;
    for (int b = h * 128; b < h * 128 + 128; ++b) cs += colpart[b * 128 + c];
    __syncthreads();
    if (h == 0) csum[c] = cs;
    __syncthreads();
    if (h == 1) csum[c] += cs;
    __syncthreads();
    float v = (tid < 128) ? csum[tid] * csum[tid] : 0.f;
    #pragma unroll
    for (int off = 32; off; off >>= 1) v += __shfl_down(v, off);
    __shared__ float vsh[4];
    if (lane == 0) vsh[tid >> 6] = v;
    __syncthreads();
    if (tid == 0) {
        double ss = (dsh[0] + dsh[1]) + (dsh[2] + dsh[3]);
        double s2 = (double)((vsh[0] + vsh[2]));  // halves 1,3 are zero-lane waves of tid>=128? no:
        s2 = (double)vsh[0] + vsh[1] + vsh[2] + vsh[3];
        double sumL2 = 2.0 * 8192.0 * ss - 2.0 * s2;
        double bw = sumL2 / (8192.0 * 8192.0 - 8192.0) / 4.0;  // /KERNEL_MUL^(5/2)
        wsf[4] = (float)(-1.4426950408889634 / (bw * 16.0));   // c4
    }
}

// ---- M: 128x128 gram tile + fused 5-scale RBF epilogue. 8 waves/block. ----
__global__ __launch_bounds__(512, 4) void mmd_main(const unsigned short* __restrict__ xbf,
                                                   const float* __restrict__ wsf,
                                                   float* __restrict__ partial) {
    __shared__ unsigned short ldsA[128 * D];  // 32 KB
    __shared__ unsigned short ldsB[128 * D];  // 32 KB (64 KB total -> 2 blocks/CU, 16 waves)

    const float* rowsq = wsf + 33280;

    // triangular block index -> (bi <= bj)
    int t = blockIdx.x;
    int bi = (int)((129.0 - sqrt(129.0 * 129.0 - 8.0 * (double)t)) * 0.5);
    auto base = [](int b) { return (b * (129 - b)) >> 1; };
    while (base(bi + 1) <= t) ++bi;
    while (base(bi) > t) --bi;
    int bj = bi + (t - base(bi));

    const int tid = threadIdx.x, lane = tid & 63, wv = tid >> 6;
    const int quad = lane >> 4, mrow = lane & 15;

    // staging: waves 0-3 -> A tile, waves 4-7 -> B tile; xbf is pre-swizzled,
    // so addresses are fully linear (lane offset implicit in global_load_lds).
    {
        const int w4 = wv & 3;
        const unsigned short* Xt = xbf + (size_t)((wv < 4) ? bi : bj) * 128 * D;
        unsigned short* L = (wv < 4) ? ldsA : ldsB;
        #pragma unroll
        for (int j = 0; j < 8; ++j) {
            int sbase = (w4 * 8 + j) * 64;   // 16B slots, wave-uniform
            __builtin_amdgcn_global_load_lds(
                (const __attribute__((address_space(1))) void*)(Xt + (sbase + lane) * 8),
                (__attribute__((address_space(3))) void*)&L[sbase * 8], 16, 0, 0);
        }
    }
    float c4 = wsf[4];
    __syncthreads();

    const int wm = wv & 1, wn = wv >> 1;      // 2x4 wave grid: 64 rows x 32 cols per wave

    float4v accf[4][2];
    #pragma unroll
    for (int mt = 0; mt < 4; ++mt)
        #pragma unroll
        for (int nt = 0; nt < 2; ++nt)
            accf[mt][nt] = (float4v){0.f, 0.f, 0.f, 0.f};

    const int xkey = (mrow & 7);
    #pragma unroll
    for (int kc = 0; kc < 4; ++kc) {
        const int co = ((kc * 4 + quad) ^ xkey) * 8;
        short8 af[4], bfr[2];
        #pragma unroll
        for (int mt = 0; mt < 4; ++mt)
            af[mt] = *(const short8*)&ldsA[(wm * 64 + mt * 16 + mrow) * D + co];
        #pragma unroll
        for (int nt = 0; nt < 2; ++nt)
            bfr[nt] = *(const short8*)&ldsB[(wn * 32 + nt * 16 + mrow) * D + co];
        #pragma unroll
        for (int mt = 0; mt < 4; ++mt)
            #pragma unroll
            for (int nt = 0; nt < 2; ++nt)
                accf[mt][nt] = __builtin_amdgcn_mfma_f32_16x16x32_bf16(af[mt], bfr[nt], accf[mt][nt], 0, 0, 0);
    }

    // epilogue: e = exp2(fma(d, -2*c4, rA*c4 + rB*c4)); sum e^1,2,4,8,16
    const float* rsqA = rowsq + bi * 128;
    const float* rsqB = rowsq + bj * 128;
    const float cm2 = -2.f * c4;
    float part = 0.f;
    #pragma unroll
    for (int mt = 0; mt < 4; ++mt) {
        float rAc[4];
        #pragma unroll
        for (int r = 0; r < 4; ++r) rAc[r] = rsqA[wm * 64 + mt * 16 + quad * 4 + r] * c4;
        #pragma unroll
        for (int nt = 0; nt < 2; ++nt) {
            float rBc = rsqB[wn * 32 + nt * 16 + mrow] * c4;
            float4v d = accf[mt][nt];
            #pragma unroll
            for (int r = 0; r < 4; ++r) {
                float e1 = __builtin_amdgcn_exp2f(__builtin_fmaf(d[r], cm2, rAc[r] + rBc));
                float e2 = e1 * e1, e4 = e2 * e2, e8 = e4 * e4, e16 = e8 * e8;
                part += ((e1 + e2) + (e4 + e8)) + e16;
            }
        }
    }
    #pragma unroll
    for (int off = 32; off; off >>= 1) part += __shfl_down(part, off);

    __syncthreads();               // tile data dead; reuse ldsA for tiny reduction
    float* red = (float*)ldsA;
    if (lane == 0) red[wv] = part;
    __syncthreads();
    if (tid == 0) {
        float s = ((red[0] + red[1]) + (red[2] + red[3])) +
                  ((red[4] + red[5]) + (red[6] + red[7]));
        float wgt = ((bi < 32) == (bj < 32)) ? 1.f : -1.f;  // XX/YY vs XY/YX sign
        if (bi != bj) wgt *= 2.f;                           // symmetric off-diagonal
        partial[t] = wgt * s;                               // plain store, no fence
    }
}

// ---- F: reduce per-block partials in fp64, scale, emit ----
__global__ __launch_bounds__(256) void f_final(const float* __restrict__ wsf,
                                               float* __restrict__ out) {
    const float* partial = wsf + 41472;
    int tid = threadIdx.x, lane = tid & 63;
    double s = 0.0;
    for (int i = tid; i < N_TILES; i += 256) s += (double)partial[i];
    #pragma unroll
    for (int off = 32; off; off >>= 1) s += __shfl_down(s, off);
    __shared__ double r4[4];
    if (lane == 0) r4[tid >> 6] = s;
    __syncthreads();
    if (tid == 0)
        out[0] = (float)(((r4[0] + r4[1]) + (r4[2] + r4[3])) * (1.0 / (4096.0 * 4096.0)));
}

extern "C" void kernel_launch(void* const* d_in, const int* in_sizes, int n_in,
                              void* d_out, int out_size, void* d_ws, size_t ws_size,
                              hipStream_t stream) {
    const float* src = (const float*)d_in[0];
    const float* tgt = (const float*)d_in[1];
    float* wsf = (float*)d_ws;
    unsigned int* xbf = (unsigned int*)(wsf + 65536);   // byte 256K, 2 MB
    float* partial = wsf + 41472;

    hipLaunchKernelGGL(k_stats, dim3(256), dim3(256), 0, stream, src, tgt, wsf, xbf);
    hipLaunchKernelGGL(k_c4, dim3(1), dim3(256), 0, stream, wsf);
    hipLaunchKernelGGL(mmd_main, dim3(N_TILES), dim3(512), 0, stream,
                       (const unsigned short*)xbf, wsf, partial);
    hipLaunchKernelGGL(f_final, dim3(1), dim3(256), 0, stream, wsf, (float*)d_out);
}